// Round 8
// baseline (336.589 us; speedup 1.0000x reference)
//
#include <hip/hip_runtime.h>
#include <hip/hip_bf16.h>
#include <cfloat>

__device__ __forceinline__ float lrelu(float x, float a) { return x > 0.0f ? x : a * x; }

// fp32 -> bf16 round-to-nearest-even (bit pattern)
__device__ __forceinline__ unsigned short f2bf(float f) {
    unsigned u = __float_as_uint(f);
    unsigned r = (u + 0x7FFFu + ((u >> 16) & 1u)) >> 16;
    return (unsigned short)r;
}
__device__ __forceinline__ float bf2f(unsigned short u) {
    return __uint_as_float((unsigned)u << 16);
}

typedef __attribute__((ext_vector_type(8))) short short8;
typedef __attribute__((ext_vector_type(4))) float f32x4;

#define BN_RSQ 0.99999500003749968750f  // 1/sqrt(1+1e-5)
#define SCAN_B 256

// ---------- fast zero ----------
__global__ void zero_ws(uint4* __restrict__ p, int n16)
{
    int t = blockIdx.x * blockDim.x + threadIdx.x;
    if (t < n16) p[t] = make_uint4(0u, 0u, 0u, 0u);
}

// ---------- weight conversion into MFMA fragment-order (coalesced) layouts ----------
__global__ void conv_wsage(const float* __restrict__ Wl, const float* __restrict__ Wr,
                           unsigned short* __restrict__ Btp)
{
    int idx = blockIdx.x * blockDim.x + threadIdx.x;
    if (idx >= 256 * 1024) return;
    int j    = idx & 7;
    int lane = (idx >> 3) & 63;
    int fn   = (idx >> 9) & 3;
    int wid  = (idx >> 11) & 3;
    int t    = idx >> 13;                    // kstep 0..31
    int c = wid * 64 + fn * 16 + (lane & 15);
    int k = t * 32 + (lane >> 4) * 8 + j;
    float v = (c < 128) ? Wl[(size_t)k * 128 + c] : Wr[(size_t)k * 128 + (c - 128)];
    Btp[idx] = f2bf(v);
}

__global__ void conv_wfc1(const float* __restrict__ fc1W, unsigned short* __restrict__ Bt1p)
{
    int idx = blockIdx.x * blockDim.x + threadIdx.x;
    if (idx >= 36864) return;
    int j    = idx & 7;
    int lane = (idx >> 3) & 63;
    int fn   = (idx >> 9) & 3;
    int q    = idx >> 11;                    // t*3 + wid, 0..17
    int wid = q % 3, t = q / 3;
    int c = wid * 64 + fn * 16 + (lane & 15);
    int k = t * 32 + (lane >> 4) * 8 + j;
    float v = (c < 168 && k < 168) ? fc1W[(size_t)k * 168 + c] : 0.0f;
    Bt1p[idx] = f2bf(v);
}

// ---------- SAGE GEMM via MFMA: SINGLE-WAVE blocks (no barriers at all) ----------
// Each wave: 32 rows x 128 cols. Private LDS double-buffer for the A chunk.
// No __syncthreads -> compiler emits counted vmcnt/lgkmcnt; A-prefetch survives.
// idx mapping keeps the two col-halves of a row-tile on the SAME XCD (bid mod 8).
__global__ __launch_bounds__(64) void gemm_sage_mfma(
    const float* __restrict__ A, const unsigned short* __restrict__ Btp,
    unsigned short* __restrict__ P, int M, int RT)
{
    __shared__ unsigned short As2[2][32][72];   // +8 pad -> 2-way (free) on ds_read_b128
    const int lane = threadIdx.x;
    const int idx  = blockIdx.x;
    const int rowtile = (idx >> 4) * 8 + (idx & 7);
    const int colhalf = (idx >> 3) & 1;
    if (rowtile >= RT) return;
    const int m0 = rowtile * 32;
    const int l16 = lane & 15, g = lane >> 4;
    const short8* Bv = reinterpret_cast<const short8*>(Btp);

    f32x4 acc[2][8] = {};
    float4 rnext[8];

    // chunk load: 32 rows x 64 k fp32 -> 8 float4/lane (lane covers 64B of one row)
    auto loadA = [&](int k0, float4 (&r)[8]) {
#pragma unroll
        for (int i = 0; i < 8; ++i) {
            int ar = m0 + i * 4 + g;
            r[i] = make_float4(0.f, 0.f, 0.f, 0.f);
            if (ar < M) r[i] = *reinterpret_cast<const float4*>(&A[(size_t)ar * 1024 + k0 + l16 * 4]);
        }
    };
    auto storeA = [&](int buf, const float4 (&r)[8]) {
#pragma unroll
        for (int i = 0; i < 8; ++i) {
            int row = i * 4 + g;
            ushort4 u;
            u.x = f2bf(r[i].x); u.y = f2bf(r[i].y); u.z = f2bf(r[i].z); u.w = f2bf(r[i].w);
            *reinterpret_cast<ushort4*>(&As2[buf][row][l16 * 4]) = u;
        }
    };

    loadA(0, rnext);
    storeA(0, rnext);

    for (int c = 0; c < 16; ++c) {
        const int buf = c & 1;
        if (c < 15) loadA((c + 1) * 64, rnext);   // in-flight across this chunk's MFMA
#pragma unroll
        for (int t = 0; t < 2; ++t) {
            const int ks = c * 2 + t;
            short8 afr[2], bfr[8];
#pragma unroll
            for (int fm = 0; fm < 2; ++fm)
                afr[fm] = *reinterpret_cast<const short8*>(&As2[buf][fm * 16 + l16][t * 32 + g * 8]);
#pragma unroll
            for (int fnn = 0; fnn < 8; ++fnn) {
                int wo = colhalf * 2 + (fnn >> 2), fo = fnn & 3;
                bfr[fnn] = Bv[((ks * 4 + wo) * 4 + fo) * 64 + lane];
            }
#pragma unroll
            for (int fm = 0; fm < 2; ++fm)
#pragma unroll
                for (int fnn = 0; fnn < 8; ++fnn)
                    acc[fm][fnn] = __builtin_amdgcn_mfma_f32_16x16x32_bf16(
                        afr[fm], bfr[fnn], acc[fm][fnn], 0, 0, 0);
        }
        if (c < 15) storeA(buf ^ 1, rnext);
    }

#pragma unroll
    for (int fm = 0; fm < 2; ++fm) {
#pragma unroll
        for (int rr = 0; rr < 4; ++rr) {
            int row = m0 + fm * 16 + g * 4 + rr;
            if (row < M) {
#pragma unroll
                for (int fnn = 0; fnn < 8; ++fnn)
                    P[(size_t)row * 256 + colhalf * 128 + fnn * 16 + l16] = f2bf(acc[fm][fnn][rr]);
            }
        }
    }
}

// ---------- MLP head via MFMA (z bf16 + addf direct) ----------
__global__ __launch_bounds__(256) void mlp_mfma(
    const unsigned short* __restrict__ z, const float* __restrict__ addf,
    const unsigned short* __restrict__ Bt1p,
    const float* __restrict__ fc1b, const float* __restrict__ bnfg, const float* __restrict__ bnfb,
    const float* __restrict__ fc2W, const float* __restrict__ fc2b,
    float* __restrict__ out, int M)
{
    __shared__ __align__(16) char smem[64 * 169 * 4];
    unsigned short (*zs)[200] = reinterpret_cast<unsigned short(*)[200]>(smem);
    float (*ts)[169] = reinterpret_cast<float(*)[169]>(smem);
    const int tid = threadIdx.x;
    const int wid = tid >> 6, lane = tid & 63;
    const int m0 = blockIdx.x * 64;
    const int l16 = lane & 15, g = lane >> 4;
    const short8* Bv = reinterpret_cast<const short8*>(Bt1p);

#pragma unroll
    for (int p = 0; p < 13; ++p) {
        int idx = p * 256 + tid;
        if (idx < 3200) {
            int row = idx / 50, c4 = (idx % 50) * 4;
            int ar = m0 + row;
            ushort4 u; u.x = 0; u.y = 0; u.z = 0; u.w = 0;
            if (ar < M) {
                if (c4 < 148) {
                    u = *reinterpret_cast<const ushort4*>(&z[(size_t)ar * 168 + c4]);
                } else if (c4 < 168) {
                    float4 v = *reinterpret_cast<const float4*>(&addf[(size_t)ar * 20 + (c4 - 148)]);
                    u.x = f2bf(v.x); u.y = f2bf(v.y); u.z = f2bf(v.z); u.w = f2bf(v.w);
                }
            }
            *reinterpret_cast<ushort4*>(&zs[row][c4]) = u;
        }
    }
    __syncthreads();

    f32x4 acc[4][4] = {};
    if (wid < 3) {
#pragma unroll
        for (int t = 0; t < 6; ++t) {
            short8 afr[4], bfr[4];
#pragma unroll
            for (int fm = 0; fm < 4; ++fm)
                afr[fm] = *reinterpret_cast<const short8*>(&zs[fm * 16 + l16][t * 32 + g * 8]);
#pragma unroll
            for (int fn = 0; fn < 4; ++fn)
                bfr[fn] = Bv[((t * 3 + wid) * 4 + fn) * 64 + lane];
#pragma unroll
            for (int fm = 0; fm < 4; ++fm)
#pragma unroll
                for (int fn = 0; fn < 4; ++fn)
                    acc[fm][fn] = __builtin_amdgcn_mfma_f32_16x16x32_bf16(
                        afr[fm], bfr[fn], acc[fm][fn], 0, 0, 0);
        }
    }
    __syncthreads();
    if (wid < 3) {
        const int colbase = wid * 64 + l16;
#pragma unroll
        for (int fm = 0; fm < 4; ++fm) {
#pragma unroll
            for (int r = 0; r < 4; ++r) {
                int rr = fm * 16 + g * 4 + r;
#pragma unroll
                for (int fn = 0; fn < 4; ++fn) {
                    int col = colbase + fn * 16;
                    if (col < 168) {
                        float v = acc[fm][fn][r] + fc1b[col];
                        v = v * (bnfg[col] * BN_RSQ) + bnfb[col];
                        ts[rr][col] = fmaxf(v, 0.0f);
                    }
                }
            }
        }
    }
    __syncthreads();
    if (tid < 192) {
        int r = tid & 63, c = tid >> 6;
        float acc2 = fc2b[c];
#pragma unroll 4
        for (int k = 0; k < 168; ++k) acc2 += ts[r][k] * fc2W[k * 3 + c];
        int row = m0 + r;
        if (row < M) out[(size_t)row * 3 + c] = acc2;
    }
}

// ---------- histograms + edge attrs ----------
__global__ void edge_count(const int* __restrict__ e1d, const int* __restrict__ e2d,
                           const float* __restrict__ ef,
                           int* __restrict__ cnt1, int* __restrict__ cnt2,
                           float* __restrict__ easum, float* __restrict__ eaext, int E)
{
    int e = blockIdx.x * blockDim.x + threadIdx.x;
    if (e >= E) return;
    atomicAdd(&cnt1[e1d[e]], 1);
    int d2 = e2d[e];
    atomicAdd(&cnt2[d2], 1);
    float a = ef[e];
    atomicAdd(&easum[d2], a);
    eaext[e] = a;
}

// ---------- exclusive scans (y-fused for both CSRs) ----------
__global__ void scan1(const int* __restrict__ cnt1, const int* __restrict__ cnt2,
                      int* __restrict__ off1, int* __restrict__ off2,
                      int* __restrict__ bsum1, int* __restrict__ bsum2, int M)
{
    __shared__ int sh[SCAN_B];
    int y = blockIdx.y;
    const int* cnt = y ? cnt2 : cnt1;
    int* excl = y ? off2 : off1;
    int* bsum = y ? bsum2 : bsum1;
    int i = blockIdx.x * SCAN_B + threadIdx.x;
    int v = (i < M) ? cnt[i] + y : 0;
    sh[threadIdx.x] = v;
    __syncthreads();
    for (int o = 1; o < SCAN_B; o <<= 1) {
        int t = (threadIdx.x >= o) ? sh[threadIdx.x - o] : 0;
        __syncthreads();
        sh[threadIdx.x] += t;
        __syncthreads();
    }
    if (i < M) excl[i] = sh[threadIdx.x] - v;
    if (threadIdx.x == SCAN_B - 1) bsum[blockIdx.x] = sh[threadIdx.x];
}

__global__ void scan2(int* __restrict__ bsum1, int* __restrict__ bsum2, int nb)
{
    __shared__ int sh[SCAN_B];
    int* bsum = blockIdx.y ? bsum2 : bsum1;
    int v = ((int)threadIdx.x < nb) ? bsum[threadIdx.x] : 0;
    sh[threadIdx.x] = v;
    __syncthreads();
    for (int o = 1; o < SCAN_B; o <<= 1) {
        int t = (threadIdx.x >= o) ? sh[threadIdx.x - o] : 0;
        __syncthreads();
        sh[threadIdx.x] += t;
        __syncthreads();
    }
    if ((int)threadIdx.x < nb) bsum[threadIdx.x] = sh[threadIdx.x] - v;
}

__global__ void scan3(int* __restrict__ off1, int* __restrict__ off2,
                      const int* __restrict__ bsum1, const int* __restrict__ bsum2,
                      const int* __restrict__ cnt1, const int* __restrict__ cnt2,
                      const float* __restrict__ easum, float* __restrict__ eaext,
                      int E, int M)
{
    int y = blockIdx.y;
    int* off = y ? off2 : off1;
    const int* bsum = y ? bsum2 : bsum1;
    const int* cnt = y ? cnt2 : cnt1;
    int i = blockIdx.x * SCAN_B + threadIdx.x;
    if (i < M) {
        int v = off[i] + bsum[blockIdx.x];
        off[i] = v;
        if (i == M - 1) off[M] = v + cnt[i] + y;   // sentinel (add1 == y)
        if (y) eaext[E + i] = easum[i] / fmaxf((float)cnt2[i], 1.0f);
    }
}

// ---------- fused CSR fill (both graphs; cnt used as down-counting cursor) ----------
__global__ void fill_both(const int* __restrict__ e1s, const int* __restrict__ e1d,
                          const int* __restrict__ e2d,
                          const int* __restrict__ off1, const int* __restrict__ off2,
                          int* __restrict__ cnt1, int* __restrict__ cnt2,
                          int* __restrict__ srcs1, int* __restrict__ eidx2, int E, int Eext)
{
    int t = blockIdx.x * blockDim.x + threadIdx.x;
    if (t < E) {
        int d = e1d[t];
        int pos = atomicSub(&cnt1[d], 1) - 1;
        srcs1[off1[d] + pos] = e1s[t];
    }
    int t2 = t - E;
    if (t2 >= 0 && t2 < Eext) {
        if (t2 < E) {
            int d = e2d[t2];
            int pos = atomicSub(&cnt2[d], 1) - 1;
            eidx2[off2[d] + pos] = t2;
        } else {
            int nn = t2 - E;
            eidx2[off2[nn + 1] - 1] = t2;   // self-loop takes the last slot
        }
    }
}

// ---------- SAGE gather (bf16 P), fused BN/act epilogue into bf16 z ----------
__global__ void sage_gather(const int* __restrict__ srcs1, const int* __restrict__ off1,
                            const unsigned short* __restrict__ P, const float* __restrict__ bl,
                            const float* __restrict__ bng, const float* __restrict__ bnb,
                            unsigned short* __restrict__ z, int N)
{
    int t = blockIdx.x * blockDim.x + threadIdx.x;
    if (t >= N * 32) return;
    int n = t >> 5, g = t & 31;
    int beg = off1[n], end = off1[n + 1];
    float a0 = 0.f, a1 = 0.f, a2 = 0.f, a3 = 0.f;
    for (int j = beg; j < end; ++j) {
        int s = srcs1[j];
        ushort4 v = *reinterpret_cast<const ushort4*>(&P[(size_t)s * 256 + g * 4]);
        a0 += bf2f(v.x); a1 += bf2f(v.y); a2 += bf2f(v.z); a3 += bf2f(v.w);
    }
    float inv = 1.0f / fmaxf((float)(end - beg), 1.0f);
    ushort4 pr = *reinterpret_cast<const ushort4*>(&P[(size_t)n * 256 + 128 + g * 4]);
    float a4[4] = {a0, a1, a2, a3};
    float p4[4] = {bf2f(pr.x), bf2f(pr.y), bf2f(pr.z), bf2f(pr.w)};
    ushort4 zo;
    unsigned short* zp = reinterpret_cast<unsigned short*>(&zo);
#pragma unroll
    for (int k = 0; k < 4; ++k) {
        int cc = g * 4 + k;
        float x = a4[k] * inv + bl[cc] + p4[k];
        x = x * (bng[cc] * BN_RSQ) + bnb[cc];
        zp[k] = f2bf(lrelu(x, 0.01f));
    }
    *reinterpret_cast<ushort4*>(&z[(size_t)n * 168 + g * 4]) = zo;
}

// ---------- GATv2 linear projections ----------
template <int IND, int HC>
__global__ void gat_lin(const float* __restrict__ X,
                        const float* __restrict__ Wl, const float* __restrict__ bl,
                        const float* __restrict__ Wr, const float* __restrict__ br,
                        float* __restrict__ xl, float* __restrict__ xr, int N)
{
    int t = blockIdx.x * blockDim.x + threadIdx.x;
    if (t >= N * HC) return;
    int n = t / HC, j = t % HC;
    float al = bl[j], ar = br[j];
    const float* xrow = X + (size_t)n * IND;
#pragma unroll 4
    for (int k = 0; k < IND; ++k) {
        float xv = xrow[k];
        al += xv * Wl[k * HC + j];
        ar += xv * Wr[k * HC + j];
    }
    xl[t] = al;
    xr[t] = ar;
}

// ---------- fused GATv2 per (node, head): ONE pass, online softmax ----------
template <int H, int C, int MODE>
__global__ void gat_node(const int* __restrict__ eidx2, const int* __restrict__ off2,
                         const int* __restrict__ e2s, const float* __restrict__ eaext,
                         const float* __restrict__ xl, const float* __restrict__ xr,
                         const float* __restrict__ We, const float* __restrict__ att,
                         const float* __restrict__ b,
                         const float* __restrict__ bng, const float* __restrict__ bnb,
                         void* __restrict__ outv, int E, int N)
{
    int t = blockIdx.x * blockDim.x + threadIdx.x;
    if (t >= N * H) return;
    int n = t / H, h = t % H;

    float xrc[C], atth[C], weh[C];
#pragma unroll
    for (int c = 0; c < C; ++c) {
        xrc[c]  = xr[(size_t)n * (H * C) + h * C + c];
        atth[c] = att[h * C + c];
        weh[c]  = We[h * C + c];
    }

    const int beg = off2[n], end = off2[n + 1];

    float mx = -FLT_MAX, den = 0.0f;
    float accv[C] = {};
    for (int j = beg; j < end; ++j) {
        int e = eidx2[j];
        int s = (e < E) ? e2s[e] : (e - E);
        float ea = eaext[e];
        const float* xls = xl + (size_t)s * (H * C) + h * C;
        float xv[C];
        float lg = 0.0f;
#pragma unroll
        for (int c = 0; c < C; ++c) {
            xv[c] = xls[c];
            float m = xv[c] + xrc[c] + ea * weh[c];
            lg += lrelu(m, 0.2f) * atth[c];
        }
        if (lg > mx) {
            float sc = __expf(mx - lg);
            den *= sc;
#pragma unroll
            for (int c = 0; c < C; ++c) accv[c] *= sc;
            mx = lg;
        }
        float ex = __expf(lg - mx);
        den += ex;
#pragma unroll
        for (int c = 0; c < C; ++c) accv[c] += ex * xv[c];
    }
    float inv = 1.0f / (den + 1e-16f);

#pragma unroll
    for (int c = 0; c < C; ++c) {
        int jch = h * C + c;
        float v = accv[c] * inv + b[jch];
        if (MODE == 1) {
            ((float*)outv)[(size_t)n * (H * C) + jch] = lrelu(v, 0.01f);
        } else {
            v = v * (bng[jch] * BN_RSQ) + bnb[jch];
            ((unsigned short*)outv)[(size_t)n * 168 + 128 + jch] = f2bf(lrelu(v, 0.01f));
        }
    }
}

// ---------- launch ----------
extern "C" void kernel_launch(void* const* d_in, const int* in_sizes, int n_in,
                              void* d_out, int out_size, void* d_ws, size_t ws_size,
                              hipStream_t stream)
{
    const float* features = (const float*)d_in[0];
    const int*   e1       = (const int*)d_in[1];
    const int*   e2       = (const int*)d_in[2];
    const float* ef       = (const float*)d_in[3];
    const float* addf     = (const float*)d_in[4];
    const float* sage_Wl  = (const float*)d_in[5];
    const float* sage_bl  = (const float*)d_in[6];
    const float* sage_Wr  = (const float*)d_in[7];
    const float* g1_Wl = (const float*)d_in[8];
    const float* g1_bl = (const float*)d_in[9];
    const float* g1_Wr = (const float*)d_in[10];
    const float* g1_br = (const float*)d_in[11];
    const float* g1_We = (const float*)d_in[12];
    const float* g1_att = (const float*)d_in[13];
    const float* g1_b = (const float*)d_in[14];
    const float* g2_Wl = (const float*)d_in[15];
    const float* g2_bl = (const float*)d_in[16];
    const float* g2_Wr = (const float*)d_in[17];
    const float* g2_br = (const float*)d_in[18];
    const float* g2_We = (const float*)d_in[19];
    const float* g2_att = (const float*)d_in[20];
    const float* g2_b = (const float*)d_in[21];
    const float* fc1_W = (const float*)d_in[22];
    const float* fc1_b = (const float*)d_in[23];
    const float* fc2_W = (const float*)d_in[24];
    const float* fc2_b = (const float*)d_in[25];
    const float* bnx_g = (const float*)d_in[26];
    const float* bnx_b = (const float*)d_in[27];
    const float* bny_g = (const float*)d_in[28];
    const float* bny_b = (const float*)d_in[29];
    const float* bnf_g = (const float*)d_in[30];
    const float* bnf_b = (const float*)d_in[31];

    const int N = in_sizes[0] / 1024;
    const int E = in_sizes[3];
    const int Eext = E + N;
    const int* e1s = e1, *e1d = e1 + E;
    const int* e2s = e2, *e2d = e2 + E;
    const int nb = (N + SCAN_B - 1) / SCAN_B;

    char* wb = (char*)d_ws;
    size_t off = 0;
    auto takeB = [&](size_t bytes) { char* p = wb + off; off = (off + bytes + 255) & ~(size_t)255; return p; };
    unsigned short* P = (unsigned short*)takeB((size_t)N * 256 * 2);
    unsigned short* z = (unsigned short*)takeB((size_t)N * 168 * 2);
    float* eaext = (float*)takeB((size_t)Eext * 4);
    float* xl1   = (float*)takeB((size_t)N * 40 * 4);
    float* xr1   = (float*)takeB((size_t)N * 40 * 4);
    float* y1    = (float*)takeB((size_t)N * 40 * 4);
    float* xl2   = (float*)takeB((size_t)N * 20 * 4);
    float* xr2   = (float*)takeB((size_t)N * 20 * 4);
    unsigned short* Btp  = (unsigned short*)takeB((size_t)256 * 1024 * 2);
    unsigned short* Bt1p = (unsigned short*)takeB((size_t)36864 * 2);
    char* zero_beg = wb + off;
    int* cnt1    = (int*)takeB((size_t)N * 4);
    int* cnt2    = (int*)takeB((size_t)N * 4);
    float* easum = (float*)takeB((size_t)N * 4);
    size_t zero_len = (size_t)((wb + off) - zero_beg);
    int* off1  = (int*)takeB((size_t)(N + 1) * 4);
    int* off2  = (int*)takeB((size_t)(N + 1) * 4);
    int* bsum1 = (int*)takeB(SCAN_B * 4);
    int* bsum2 = (int*)takeB(SCAN_B * 4);
    int* srcs1 = (int*)takeB((size_t)E * 4);
    int* eidx2 = (int*)takeB((size_t)Eext * 4);

    const int B = 256;
    const int n16 = (int)(zero_len / 16);
    zero_ws<<<(n16 + B - 1) / B, B, 0, stream>>>((uint4*)zero_beg, n16);

    conv_wsage<<<(256 * 1024 + B - 1) / B, B, 0, stream>>>(sage_Wl, sage_Wr, Btp);
    conv_wfc1<<<(36864 + B - 1) / B, B, 0, stream>>>(fc1_W, Bt1p);

    edge_count<<<(E + B - 1) / B, B, 0, stream>>>(e1d, e2d, ef, cnt1, cnt2, easum, eaext, E);

    scan1<<<dim3(nb, 2), SCAN_B, 0, stream>>>(cnt1, cnt2, off1, off2, bsum1, bsum2, N);
    scan2<<<dim3(1, 2), SCAN_B, 0, stream>>>(bsum1, bsum2, nb);
    scan3<<<dim3(nb, 2), SCAN_B, 0, stream>>>(off1, off2, bsum1, bsum2, cnt1, cnt2,
                                              easum, eaext, E, N);

    fill_both<<<(E + Eext + B - 1) / B, B, 0, stream>>>(e1s, e1d, e2d, off1, off2,
                                                        cnt1, cnt2, srcs1, eidx2, E, Eext);

    // SAGE GEMM: single-wave blocks, 32x128 tiles, XCD-paired col-halves
    const int RT = (N + 31) / 32;
    const int RTp = (RT + 7) & ~7;
    gemm_sage_mfma<<<RTp * 2, 64, 0, stream>>>(features, Btp, P, N, RT);
    sage_gather<<<(N * 32 + B - 1) / B, B, 0, stream>>>(srcs1, off1, P, sage_bl, bnx_g, bnx_b, z, N);

    gat_lin<20, 40><<<(N * 40 + B - 1) / B, B, 0, stream>>>(addf, g1_Wl, g1_bl, g1_Wr, g1_br, xl1, xr1, N);
    gat_node<4, 10, 1><<<(N * 4 + B - 1) / B, B, 0, stream>>>(
        eidx2, off2, e2s, eaext, xl1, xr1, g1_We, g1_att, g1_b,
        nullptr, nullptr, (void*)y1, E, N);

    gat_lin<40, 20><<<(N * 20 + B - 1) / B, B, 0, stream>>>(y1, g2_Wl, g2_bl, g2_Wr, g2_br, xl2, xr2, N);
    gat_node<4, 5, 2><<<(N * 4 + B - 1) / B, B, 0, stream>>>(
        eidx2, off2, e2s, eaext, xl2, xr2, g2_We, g2_att, g2_b,
        bny_g, bny_b, (void*)z, E, N);

    const int mtiles = (N + 63) / 64;
    mlp_mfma<<<mtiles, 256, 0, stream>>>(z, addf, Bt1p, fc1_b, bnf_g, bnf_b, fc2_W, fc2_b,
                                         (float*)d_out, N);
}

// Round 9
// 334.738 us; speedup vs baseline: 1.0055x; 1.0055x over previous
//
#include <hip/hip_runtime.h>
#include <hip/hip_bf16.h>
#include <cfloat>

__device__ __forceinline__ float lrelu(float x, float a) { return x > 0.0f ? x : a * x; }

// fp32 -> bf16 round-to-nearest-even (bit pattern)
__device__ __forceinline__ unsigned short f2bf(float f) {
    unsigned u = __float_as_uint(f);
    unsigned r = (u + 0x7FFFu + ((u >> 16) & 1u)) >> 16;
    return (unsigned short)r;
}
__device__ __forceinline__ float bf2f(unsigned short u) {
    return __uint_as_float((unsigned)u << 16);
}

typedef __attribute__((ext_vector_type(8))) short short8;
typedef __attribute__((ext_vector_type(4))) float f32x4;

#define BN_RSQ 0.99999500003749968750f  // 1/sqrt(1+1e-5)
#define SCAN_B 256

// ---------- fast zero ----------
__global__ void zero_ws(uint4* __restrict__ p, int n16)
{
    int t = blockIdx.x * blockDim.x + threadIdx.x;
    if (t < n16) p[t] = make_uint4(0u, 0u, 0u, 0u);
}

// ---------- weight conversion into MFMA fragment-order (coalesced) layouts ----------
__global__ void conv_wsage(const float* __restrict__ Wl, const float* __restrict__ Wr,
                           unsigned short* __restrict__ Btp)
{
    int idx = blockIdx.x * blockDim.x + threadIdx.x;
    if (idx >= 256 * 1024) return;
    int j    = idx & 7;
    int lane = (idx >> 3) & 63;
    int fn   = (idx >> 9) & 3;
    int wid  = (idx >> 11) & 3;
    int t    = idx >> 13;                    // kstep 0..31
    int c = wid * 64 + fn * 16 + (lane & 15);
    int k = t * 32 + (lane >> 4) * 8 + j;
    float v = (c < 128) ? Wl[(size_t)k * 128 + c] : Wr[(size_t)k * 128 + (c - 128)];
    Btp[idx] = f2bf(v);
}

__global__ void conv_wfc1(const float* __restrict__ fc1W, unsigned short* __restrict__ Bt1p)
{
    int idx = blockIdx.x * blockDim.x + threadIdx.x;
    if (idx >= 36864) return;
    int j    = idx & 7;
    int lane = (idx >> 3) & 63;
    int fn   = (idx >> 9) & 3;
    int q    = idx >> 11;                    // t*3 + wid, 0..17
    int wid = q % 3, t = q / 3;
    int c = wid * 64 + fn * 16 + (lane & 15);
    int k = t * 32 + (lane >> 4) * 8 + j;
    float v = (c < 168 && k < 168) ? fc1W[(size_t)k * 168 + c] : 0.0f;
    Bt1p[idx] = f2bf(v);
}

// ---------- SAGE GEMM via MFMA: SINGLE-WAVE blocks (no barriers at all) ----------
// Each wave: 32 rows x 128 cols. Private LDS double-buffer for the A chunk.
// No __syncthreads -> compiler emits counted vmcnt/lgkmcnt; A-prefetch survives.
// idx mapping keeps the two col-halves of a row-tile on the SAME XCD (bid mod 8).
__global__ __launch_bounds__(64) void gemm_sage_mfma(
    const float* __restrict__ A, const unsigned short* __restrict__ Btp,
    unsigned short* __restrict__ P, int M, int RT)
{
    __shared__ unsigned short As2[2][32][72];   // +8 pad -> 2-way (free) on ds_read_b128
    const int lane = threadIdx.x;
    const int idx  = blockIdx.x;
    const int rowtile = (idx >> 4) * 8 + (idx & 7);
    const int colhalf = (idx >> 3) & 1;
    if (rowtile >= RT) return;
    const int m0 = rowtile * 32;
    const int l16 = lane & 15, g = lane >> 4;
    const short8* Bv = reinterpret_cast<const short8*>(Btp);

    f32x4 acc[2][8] = {};
    float4 rnext[8];

    // chunk load: 32 rows x 64 k fp32 -> 8 float4/lane (lane covers 64B of one row)
    auto loadA = [&](int k0, float4 (&r)[8]) {
#pragma unroll
        for (int i = 0; i < 8; ++i) {
            int ar = m0 + i * 4 + g;
            r[i] = make_float4(0.f, 0.f, 0.f, 0.f);
            if (ar < M) r[i] = *reinterpret_cast<const float4*>(&A[(size_t)ar * 1024 + k0 + l16 * 4]);
        }
    };
    auto storeA = [&](int buf, const float4 (&r)[8]) {
#pragma unroll
        for (int i = 0; i < 8; ++i) {
            int row = i * 4 + g;
            ushort4 u;
            u.x = f2bf(r[i].x); u.y = f2bf(r[i].y); u.z = f2bf(r[i].z); u.w = f2bf(r[i].w);
            *reinterpret_cast<ushort4*>(&As2[buf][row][l16 * 4]) = u;
        }
    };

    loadA(0, rnext);
    storeA(0, rnext);

    for (int c = 0; c < 16; ++c) {
        const int buf = c & 1;
        if (c < 15) loadA((c + 1) * 64, rnext);   // in-flight across this chunk's MFMA
#pragma unroll
        for (int t = 0; t < 2; ++t) {
            const int ks = c * 2 + t;
            short8 afr[2], bfr[8];
#pragma unroll
            for (int fm = 0; fm < 2; ++fm)
                afr[fm] = *reinterpret_cast<const short8*>(&As2[buf][fm * 16 + l16][t * 32 + g * 8]);
#pragma unroll
            for (int fnn = 0; fnn < 8; ++fnn) {
                int wo = colhalf * 2 + (fnn >> 2), fo = fnn & 3;
                bfr[fnn] = Bv[((ks * 4 + wo) * 4 + fo) * 64 + lane];
            }
#pragma unroll
            for (int fm = 0; fm < 2; ++fm)
#pragma unroll
                for (int fnn = 0; fnn < 8; ++fnn)
                    acc[fm][fnn] = __builtin_amdgcn_mfma_f32_16x16x32_bf16(
                        afr[fm], bfr[fnn], acc[fm][fnn], 0, 0, 0);
        }
        if (c < 15) storeA(buf ^ 1, rnext);
    }

#pragma unroll
    for (int fm = 0; fm < 2; ++fm) {
#pragma unroll
        for (int rr = 0; rr < 4; ++rr) {
            int row = m0 + fm * 16 + g * 4 + rr;
            if (row < M) {
#pragma unroll
                for (int fnn = 0; fnn < 8; ++fnn)
                    P[(size_t)row * 256 + colhalf * 128 + fnn * 16 + l16] = f2bf(acc[fm][fnn][rr]);
            }
        }
    }
}

// ---------- MLP head via MFMA (z bf16 + addf direct) ----------
__global__ __launch_bounds__(256) void mlp_mfma(
    const unsigned short* __restrict__ z, const float* __restrict__ addf,
    const unsigned short* __restrict__ Bt1p,
    const float* __restrict__ fc1b, const float* __restrict__ bnfg, const float* __restrict__ bnfb,
    const float* __restrict__ fc2W, const float* __restrict__ fc2b,
    float* __restrict__ out, int M)
{
    __shared__ __align__(16) char smem[64 * 169 * 4];
    unsigned short (*zs)[200] = reinterpret_cast<unsigned short(*)[200]>(smem);
    float (*ts)[169] = reinterpret_cast<float(*)[169]>(smem);
    const int tid = threadIdx.x;
    const int wid = tid >> 6, lane = tid & 63;
    const int m0 = blockIdx.x * 64;
    const int l16 = lane & 15, g = lane >> 4;
    const short8* Bv = reinterpret_cast<const short8*>(Bt1p);

#pragma unroll
    for (int p = 0; p < 13; ++p) {
        int idx = p * 256 + tid;
        if (idx < 3200) {
            int row = idx / 50, c4 = (idx % 50) * 4;
            int ar = m0 + row;
            ushort4 u; u.x = 0; u.y = 0; u.z = 0; u.w = 0;
            if (ar < M) {
                if (c4 < 148) {
                    u = *reinterpret_cast<const ushort4*>(&z[(size_t)ar * 168 + c4]);
                } else if (c4 < 168) {
                    float4 v = *reinterpret_cast<const float4*>(&addf[(size_t)ar * 20 + (c4 - 148)]);
                    u.x = f2bf(v.x); u.y = f2bf(v.y); u.z = f2bf(v.z); u.w = f2bf(v.w);
                }
            }
            *reinterpret_cast<ushort4*>(&zs[row][c4]) = u;
        }
    }
    __syncthreads();

    f32x4 acc[4][4] = {};
    if (wid < 3) {
#pragma unroll
        for (int t = 0; t < 6; ++t) {
            short8 afr[4], bfr[4];
#pragma unroll
            for (int fm = 0; fm < 4; ++fm)
                afr[fm] = *reinterpret_cast<const short8*>(&zs[fm * 16 + l16][t * 32 + g * 8]);
#pragma unroll
            for (int fn = 0; fn < 4; ++fn)
                bfr[fn] = Bv[((t * 3 + wid) * 4 + fn) * 64 + lane];
#pragma unroll
            for (int fm = 0; fm < 4; ++fm)
#pragma unroll
                for (int fn = 0; fn < 4; ++fn)
                    acc[fm][fn] = __builtin_amdgcn_mfma_f32_16x16x32_bf16(
                        afr[fm], bfr[fn], acc[fm][fn], 0, 0, 0);
        }
    }
    __syncthreads();
    if (wid < 3) {
        const int colbase = wid * 64 + l16;
#pragma unroll
        for (int fm = 0; fm < 4; ++fm) {
#pragma unroll
            for (int r = 0; r < 4; ++r) {
                int rr = fm * 16 + g * 4 + r;
#pragma unroll
                for (int fn = 0; fn < 4; ++fn) {
                    int col = colbase + fn * 16;
                    if (col < 168) {
                        float v = acc[fm][fn][r] + fc1b[col];
                        v = v * (bnfg[col] * BN_RSQ) + bnfb[col];
                        ts[rr][col] = fmaxf(v, 0.0f);
                    }
                }
            }
        }
    }
    __syncthreads();
    if (tid < 192) {
        int r = tid & 63, c = tid >> 6;
        float acc2 = fc2b[c];
#pragma unroll 4
        for (int k = 0; k < 168; ++k) acc2 += ts[r][k] * fc2W[k * 3 + c];
        int row = m0 + r;
        if (row < M) out[(size_t)row * 3 + c] = acc2;
    }
}

// ---------- histograms + edge attrs ----------
__global__ void edge_count(const int* __restrict__ e1d, const int* __restrict__ e2d,
                           const float* __restrict__ ef,
                           int* __restrict__ cnt1, int* __restrict__ cnt2,
                           float* __restrict__ easum, float* __restrict__ eaext, int E)
{
    int e = blockIdx.x * blockDim.x + threadIdx.x;
    if (e >= E) return;
    atomicAdd(&cnt1[e1d[e]], 1);
    int d2 = e2d[e];
    atomicAdd(&cnt2[d2], 1);
    float a = ef[e];
    atomicAdd(&easum[d2], a);
    eaext[e] = a;
}

// ---------- exclusive scans (y-fused for both CSRs) ----------
__global__ void scan1(const int* __restrict__ cnt1, const int* __restrict__ cnt2,
                      int* __restrict__ off1, int* __restrict__ off2,
                      int* __restrict__ bsum1, int* __restrict__ bsum2, int M)
{
    __shared__ int sh[SCAN_B];
    int y = blockIdx.y;
    const int* cnt = y ? cnt2 : cnt1;
    int* excl = y ? off2 : off1;
    int* bsum = y ? bsum2 : bsum1;
    int i = blockIdx.x * SCAN_B + threadIdx.x;
    int v = (i < M) ? cnt[i] + y : 0;
    sh[threadIdx.x] = v;
    __syncthreads();
    for (int o = 1; o < SCAN_B; o <<= 1) {
        int t = (threadIdx.x >= o) ? sh[threadIdx.x - o] : 0;
        __syncthreads();
        sh[threadIdx.x] += t;
        __syncthreads();
    }
    if (i < M) excl[i] = sh[threadIdx.x] - v;
    if (threadIdx.x == SCAN_B - 1) bsum[blockIdx.x] = sh[threadIdx.x];
}

__global__ void scan2(int* __restrict__ bsum1, int* __restrict__ bsum2, int nb)
{
    __shared__ int sh[SCAN_B];
    int* bsum = blockIdx.y ? bsum2 : bsum1;
    int v = ((int)threadIdx.x < nb) ? bsum[threadIdx.x] : 0;
    sh[threadIdx.x] = v;
    __syncthreads();
    for (int o = 1; o < SCAN_B; o <<= 1) {
        int t = (threadIdx.x >= o) ? sh[threadIdx.x - o] : 0;
        __syncthreads();
        sh[threadIdx.x] += t;
        __syncthreads();
    }
    if ((int)threadIdx.x < nb) bsum[threadIdx.x] = sh[threadIdx.x] - v;
}

__global__ void scan3(int* __restrict__ off1, int* __restrict__ off2,
                      const int* __restrict__ bsum1, const int* __restrict__ bsum2,
                      const int* __restrict__ cnt1, const int* __restrict__ cnt2,
                      const float* __restrict__ easum, float* __restrict__ eaext,
                      int E, int M)
{
    int y = blockIdx.y;
    int* off = y ? off2 : off1;
    const int* bsum = y ? bsum2 : bsum1;
    const int* cnt = y ? cnt2 : cnt1;
    int i = blockIdx.x * SCAN_B + threadIdx.x;
    if (i < M) {
        int v = off[i] + bsum[blockIdx.x];
        off[i] = v;
        if (i == M - 1) off[M] = v + cnt[i] + y;   // sentinel (add1 == y)
        if (y) eaext[E + i] = easum[i] / fmaxf((float)cnt2[i], 1.0f);
    }
}

// ---------- fused CSR fill (both graphs; cnt used as down-counting cursor) ----------
__global__ void fill_both(const int* __restrict__ e1s, const int* __restrict__ e1d,
                          const int* __restrict__ e2d,
                          const int* __restrict__ off1, const int* __restrict__ off2,
                          int* __restrict__ cnt1, int* __restrict__ cnt2,
                          int* __restrict__ srcs1, int* __restrict__ eidx2, int E, int Eext)
{
    int t = blockIdx.x * blockDim.x + threadIdx.x;
    if (t < E) {
        int d = e1d[t];
        int pos = atomicSub(&cnt1[d], 1) - 1;
        srcs1[off1[d] + pos] = e1s[t];
    }
    int t2 = t - E;
    if (t2 >= 0 && t2 < Eext) {
        if (t2 < E) {
            int d = e2d[t2];
            int pos = atomicSub(&cnt2[d], 1) - 1;
            eidx2[off2[d] + pos] = t2;
        } else {
            int nn = t2 - E;
            eidx2[off2[nn + 1] - 1] = t2;   // self-loop takes the last slot
        }
    }
}

// ---------- SAGE gather (bf16 P), fused BN/act epilogue into bf16 z ----------
__global__ void sage_gather(const int* __restrict__ srcs1, const int* __restrict__ off1,
                            const unsigned short* __restrict__ P, const float* __restrict__ bl,
                            const float* __restrict__ bng, const float* __restrict__ bnb,
                            unsigned short* __restrict__ z, int N)
{
    int t = blockIdx.x * blockDim.x + threadIdx.x;
    if (t >= N * 32) return;
    int n = t >> 5, g = t & 31;
    int beg = off1[n], end = off1[n + 1];
    float a0 = 0.f, a1 = 0.f, a2 = 0.f, a3 = 0.f;
    for (int j = beg; j < end; ++j) {
        int s = srcs1[j];
        ushort4 v = *reinterpret_cast<const ushort4*>(&P[(size_t)s * 256 + g * 4]);
        a0 += bf2f(v.x); a1 += bf2f(v.y); a2 += bf2f(v.z); a3 += bf2f(v.w);
    }
    float inv = 1.0f / fmaxf((float)(end - beg), 1.0f);
    ushort4 pr = *reinterpret_cast<const ushort4*>(&P[(size_t)n * 256 + 128 + g * 4]);
    float a4[4] = {a0, a1, a2, a3};
    float p4[4] = {bf2f(pr.x), bf2f(pr.y), bf2f(pr.z), bf2f(pr.w)};
    ushort4 zo;
    unsigned short* zp = reinterpret_cast<unsigned short*>(&zo);
#pragma unroll
    for (int k = 0; k < 4; ++k) {
        int cc = g * 4 + k;
        float x = a4[k] * inv + bl[cc] + p4[k];
        x = x * (bng[cc] * BN_RSQ) + bnb[cc];
        zp[k] = f2bf(lrelu(x, 0.01f));
    }
    *reinterpret_cast<ushort4*>(&z[(size_t)n * 168 + g * 4]) = zo;
}

// ---------- GATv2 linear projections ----------
template <int IND, int HC>
__global__ void gat_lin(const float* __restrict__ X,
                        const float* __restrict__ Wl, const float* __restrict__ bl,
                        const float* __restrict__ Wr, const float* __restrict__ br,
                        float* __restrict__ xl, float* __restrict__ xr, int N)
{
    int t = blockIdx.x * blockDim.x + threadIdx.x;
    if (t >= N * HC) return;
    int n = t / HC, j = t % HC;
    float al = bl[j], ar = br[j];
    const float* xrow = X + (size_t)n * IND;
#pragma unroll 4
    for (int k = 0; k < IND; ++k) {
        float xv = xrow[k];
        al += xv * Wl[k * HC + j];
        ar += xv * Wr[k * HC + j];
    }
    xl[t] = al;
    xr[t] = ar;
}

// ---------- fused GATv2 per (node, head): ONE pass, online softmax ----------
template <int H, int C, int MODE>
__global__ void gat_node(const int* __restrict__ eidx2, const int* __restrict__ off2,
                         const int* __restrict__ e2s, const float* __restrict__ eaext,
                         const float* __restrict__ xl, const float* __restrict__ xr,
                         const float* __restrict__ We, const float* __restrict__ att,
                         const float* __restrict__ b,
                         const float* __restrict__ bng, const float* __restrict__ bnb,
                         void* __restrict__ outv, int E, int N)
{
    int t = blockIdx.x * blockDim.x + threadIdx.x;
    if (t >= N * H) return;
    int n = t / H, h = t % H;

    float xrc[C], atth[C], weh[C];
#pragma unroll
    for (int c = 0; c < C; ++c) {
        xrc[c]  = xr[(size_t)n * (H * C) + h * C + c];
        atth[c] = att[h * C + c];
        weh[c]  = We[h * C + c];
    }

    const int beg = off2[n], end = off2[n + 1];

    float mx = -FLT_MAX, den = 0.0f;
    float accv[C] = {};
    for (int j = beg; j < end; ++j) {
        int e = eidx2[j];
        int s = (e < E) ? e2s[e] : (e - E);
        float ea = eaext[e];
        const float* xls = xl + (size_t)s * (H * C) + h * C;
        float xv[C];
        float lg = 0.0f;
#pragma unroll
        for (int c = 0; c < C; ++c) {
            xv[c] = xls[c];
            float m = xv[c] + xrc[c] + ea * weh[c];
            lg += lrelu(m, 0.2f) * atth[c];
        }
        if (lg > mx) {
            float sc = __expf(mx - lg);
            den *= sc;
#pragma unroll
            for (int c = 0; c < C; ++c) accv[c] *= sc;
            mx = lg;
        }
        float ex = __expf(lg - mx);
        den += ex;
#pragma unroll
        for (int c = 0; c < C; ++c) accv[c] += ex * xv[c];
    }
    float inv = 1.0f / (den + 1e-16f);

#pragma unroll
    for (int c = 0; c < C; ++c) {
        int jch = h * C + c;
        float v = accv[c] * inv + b[jch];
        if (MODE == 1) {
            ((float*)outv)[(size_t)n * (H * C) + jch] = lrelu(v, 0.01f);
        } else {
            v = v * (bng[jch] * BN_RSQ) + bnb[jch];
            ((unsigned short*)outv)[(size_t)n * 168 + 128 + jch] = f2bf(lrelu(v, 0.01f));
        }
    }
}

// ---------- launch ----------
extern "C" void kernel_launch(void* const* d_in, const int* in_sizes, int n_in,
                              void* d_out, int out_size, void* d_ws, size_t ws_size,
                              hipStream_t stream)
{
    const float* features = (const float*)d_in[0];
    const int*   e1       = (const int*)d_in[1];
    const int*   e2       = (const int*)d_in[2];
    const float* ef       = (const float*)d_in[3];
    const float* addf     = (const float*)d_in[4];
    const float* sage_Wl  = (const float*)d_in[5];
    const float* sage_bl  = (const float*)d_in[6];
    const float* sage_Wr  = (const float*)d_in[7];
    const float* g1_Wl = (const float*)d_in[8];
    const float* g1_bl = (const float*)d_in[9];
    const float* g1_Wr = (const float*)d_in[10];
    const float* g1_br = (const float*)d_in[11];
    const float* g1_We = (const float*)d_in[12];
    const float* g1_att = (const float*)d_in[13];
    const float* g1_b = (const float*)d_in[14];
    const float* g2_Wl = (const float*)d_in[15];
    const float* g2_bl = (const float*)d_in[16];
    const float* g2_Wr = (const float*)d_in[17];
    const float* g2_br = (const float*)d_in[18];
    const float* g2_We = (const float*)d_in[19];
    const float* g2_att = (const float*)d_in[20];
    const float* g2_b = (const float*)d_in[21];
    const float* fc1_W = (const float*)d_in[22];
    const float* fc1_b = (const float*)d_in[23];
    const float* fc2_W = (const float*)d_in[24];
    const float* fc2_b = (const float*)d_in[25];
    const float* bnx_g = (const float*)d_in[26];
    const float* bnx_b = (const float*)d_in[27];
    const float* bny_g = (const float*)d_in[28];
    const float* bny_b = (const float*)d_in[29];
    const float* bnf_g = (const float*)d_in[30];
    const float* bnf_b = (const float*)d_in[31];

    const int N = in_sizes[0] / 1024;
    const int E = in_sizes[3];
    const int Eext = E + N;
    const int* e1s = e1, *e1d = e1 + E;
    const int* e2s = e2, *e2d = e2 + E;
    const int nb = (N + SCAN_B - 1) / SCAN_B;

    char* wb = (char*)d_ws;
    size_t off = 0;
    auto takeB = [&](size_t bytes) { char* p = wb + off; off = (off + bytes + 255) & ~(size_t)255; return p; };
    unsigned short* P = (unsigned short*)takeB((size_t)N * 256 * 2);
    unsigned short* z = (unsigned short*)takeB((size_t)N * 168 * 2);
    float* eaext = (float*)takeB((size_t)Eext * 4);
    float* xl1   = (float*)takeB((size_t)N * 40 * 4);
    float* xr1   = (float*)takeB((size_t)N * 40 * 4);
    float* y1    = (float*)takeB((size_t)N * 40 * 4);
    float* xl2   = (float*)takeB((size_t)N * 20 * 4);
    float* xr2   = (float*)takeB((size_t)N * 20 * 4);
    unsigned short* Btp  = (unsigned short*)takeB((size_t)256 * 1024 * 2);
    unsigned short* Bt1p = (unsigned short*)takeB((size_t)36864 * 2);
    char* zero_beg = wb + off;
    int* cnt1    = (int*)takeB((size_t)N * 4);
    int* cnt2    = (int*)takeB((size_t)N * 4);
    float* easum = (float*)takeB((size_t)N * 4);
    size_t zero_len = (size_t)((wb + off) - zero_beg);
    int* off1  = (int*)takeB((size_t)(N + 1) * 4);
    int* off2  = (int*)takeB((size_t)(N + 1) * 4);
    int* bsum1 = (int*)takeB(SCAN_B * 4);
    int* bsum2 = (int*)takeB(SCAN_B * 4);
    int* srcs1 = (int*)takeB((size_t)E * 4);
    int* eidx2 = (int*)takeB((size_t)Eext * 4);

    const int B = 256;
    const int n16 = (int)(zero_len / 16);
    zero_ws<<<(n16 + B - 1) / B, B, 0, stream>>>((uint4*)zero_beg, n16);

    conv_wsage<<<(256 * 1024 + B - 1) / B, B, 0, stream>>>(sage_Wl, sage_Wr, Btp);
    conv_wfc1<<<(36864 + B - 1) / B, B, 0, stream>>>(fc1_W, Bt1p);

    edge_count<<<(E + B - 1) / B, B, 0, stream>>>(e1d, e2d, ef, cnt1, cnt2, easum, eaext, E);

    scan1<<<dim3(nb, 2), SCAN_B, 0, stream>>>(cnt1, cnt2, off1, off2, bsum1, bsum2, N);
    scan2<<<dim3(1, 2), SCAN_B, 0, stream>>>(bsum1, bsum2, nb);
    scan3<<<dim3(nb, 2), SCAN_B, 0, stream>>>(off1, off2, bsum1, bsum2, cnt1, cnt2,
                                              easum, eaext, E, N);

    fill_both<<<(E + Eext + B - 1) / B, B, 0, stream>>>(e1s, e1d, e2d, off1, off2,
                                                        cnt1, cnt2, srcs1, eidx2, E, Eext);

    // SAGE GEMM: single-wave blocks, 32x128 tiles, XCD-paired col-halves
    const int RT = (N + 31) / 32;
    const int RTp = (RT + 7) & ~7;
    gemm_sage_mfma<<<RTp * 2, 64, 0, stream>>>(features, Btp, P, N, RT);
    sage_gather<<<(N * 32 + B - 1) / B, B, 0, stream>>>(srcs1, off1, P, sage_bl, bnx_g, bnx_b, z, N);

    gat_lin<20, 40><<<(N * 40 + B - 1) / B, B, 0, stream>>>(addf, g1_Wl, g1_bl, g1_Wr, g1_br, xl1, xr1, N);
    gat_node<4, 10, 1><<<(N * 4 + B - 1) / B, B, 0, stream>>>(
        eidx2, off2, e2s, eaext, xl1, xr1, g1_We, g1_att, g1_b,
        nullptr, nullptr, (void*)y1, E, N);

    gat_lin<40, 20><<<(N * 20 + B - 1) / B, B, 0, stream>>>(y1, g2_Wl, g2_bl, g2_Wr, g2_br, xl2, xr2, N);
    gat_node<4, 5, 2><<<(N * 4 + B - 1) / B, B, 0, stream>>>(
        eidx2, off2, e2s, eaext, xl2, xr2, g2_We, g2_att, g2_b,
        bny_g, bny_b, (void*)z, E, N);

    const int mtiles = (N + 63) / 64;
    mlp_mfma<<<mtiles, 256, 0, stream>>>(z, addf, Bt1p, fc1_b, bnf_g, bnf_b, fc2_W, fc2_b,
                                         (float*)d_out, N);
}

// Round 10
// 292.614 us; speedup vs baseline: 1.1503x; 1.1440x over previous
//
#include <hip/hip_runtime.h>
#include <hip/hip_bf16.h>
#include <cfloat>

__device__ __forceinline__ float lrelu(float x, float a) { return x > 0.0f ? x : a * x; }

// fp32 -> bf16 round-to-nearest-even (bit pattern)
__device__ __forceinline__ unsigned short f2bf(float f) {
    unsigned u = __float_as_uint(f);
    unsigned r = (u + 0x7FFFu + ((u >> 16) & 1u)) >> 16;
    return (unsigned short)r;
}
__device__ __forceinline__ float bf2f(unsigned short u) {
    return __uint_as_float((unsigned)u << 16);
}

typedef __attribute__((ext_vector_type(8))) short short8;
typedef __attribute__((ext_vector_type(4))) float f32x4;

#define BN_RSQ 0.99999500003749968750f  // 1/sqrt(1+1e-5)
#define SCAN_B 256

// ---------- fast zero ----------
__global__ void zero_ws(uint4* __restrict__ p, int n16)
{
    int t = blockIdx.x * blockDim.x + threadIdx.x;
    if (t < n16) p[t] = make_uint4(0u, 0u, 0u, 0u);
}

// ---------- fused prep: SAGE W pack + fc1 W pack + GAT lin W packs + edge histogram ----------
__global__ void prep_all(const float* __restrict__ sWl, const float* __restrict__ sWr,
                         unsigned short* __restrict__ Btp,
                         const float* __restrict__ fc1W, unsigned short* __restrict__ Bt1p,
                         const float* __restrict__ g1Wl, const float* __restrict__ g1Wr,
                         unsigned short* __restrict__ Bg1,
                         const float* __restrict__ g2Wl, const float* __restrict__ g2Wr,
                         unsigned short* __restrict__ Bg2,
                         const int* __restrict__ e1d, const int* __restrict__ e2d,
                         const float* __restrict__ ef,
                         int* __restrict__ cnt1, int* __restrict__ cnt2,
                         float* __restrict__ easum, float* __restrict__ eaext, int E)
{
    int idx = blockIdx.x * blockDim.x + threadIdx.x;
    if (idx < 262144) {
        // SAGE B: [((kstep*4+wid)*4+fn)*64+lane] short8; c=wid*64+fn*16+(lane&15), k=kstep*32+(lane>>4)*8+j
        int j = idx & 7, lane = (idx >> 3) & 63, fn = (idx >> 9) & 3, wid = (idx >> 11) & 3, t = idx >> 13;
        int c = wid * 64 + fn * 16 + (lane & 15);
        int k = t * 32 + (lane >> 4) * 8 + j;
        float v = (c < 128) ? sWl[(size_t)k * 128 + c] : sWr[(size_t)k * 128 + (c - 128)];
        Btp[idx] = f2bf(v);
        return;
    }
    idx -= 262144;
    if (idx < 36864) {
        // fc1 B: q = t*3+wid
        int j = idx & 7, lane = (idx >> 3) & 63, fn = (idx >> 9) & 3, q = idx >> 11;
        int wid = q % 3, t = q / 3;
        int c = wid * 64 + fn * 16 + (lane & 15);
        int k = t * 32 + (lane >> 4) * 8 + j;
        float v = (c < 168 && k < 168) ? fc1W[(size_t)k * 168 + c] : 0.0f;
        Bt1p[idx] = f2bf(v);
        return;
    }
    idx -= 36864;
    if (idx < 2560) {
        // GAT1 lin B: 1 kstep, 5 frags, cols 80 = [Wl(40) | Wr(40)], K=20 pad 32
        int j = idx & 7, lane = (idx >> 3) & 63, fn = idx >> 9;
        int c = fn * 16 + (lane & 15);
        int k = (lane >> 4) * 8 + j;
        float v = 0.0f;
        if (k < 20) v = (c < 40) ? g1Wl[(size_t)k * 40 + c] : g1Wr[(size_t)k * 40 + (c - 40)];
        Bg1[idx] = f2bf(v);
        return;
    }
    idx -= 2560;
    if (idx < 3072) {
        // GAT2 lin B: 2 ksteps, 3 frags, cols 48 = [Wl(20) | Wr(20) | pad], K=40 pad 64
        int j = idx & 7, lane = (idx >> 3) & 63, q = idx >> 9;
        int fn = q % 3, t = q / 3;
        int c = fn * 16 + (lane & 15);
        int k = t * 32 + (lane >> 4) * 8 + j;
        float v = 0.0f;
        if (k < 40 && c < 40) v = (c < 20) ? g2Wl[(size_t)k * 20 + c] : g2Wr[(size_t)k * 20 + (c - 20)];
        Bg2[idx] = f2bf(v);
        return;
    }
    idx -= 3072;
    if (idx < E) {
        atomicAdd(&cnt1[e1d[idx]], 1);
        int d2 = e2d[idx];
        atomicAdd(&cnt2[d2], 1);
        float a = ef[idx];
        atomicAdd(&easum[d2], a);
        eaext[idx] = a;
    }
}

// ---------- SAGE GEMM via MFMA (R5 structure: 4 waves, 64x256, 2-deep A prefetch, bf16 P) ----------
__global__ __launch_bounds__(256) void gemm_sage_mfma(
    const float* __restrict__ A, const unsigned short* __restrict__ Btp,
    unsigned short* __restrict__ P, int M)
{
    __shared__ unsigned short As2[2][64][72];
    const int tid = threadIdx.x;
    const int wid = tid >> 6, lane = tid & 63;
    const int m0 = blockIdx.x * 64;
    const int l16 = lane & 15, g = lane >> 4;
    const int colbase = wid * 64 + l16;
    const short8* Bv = reinterpret_cast<const short8*>(Btp);
    const int srow = tid >> 4, scol = (tid & 15) * 4;

    f32x4 acc[4][4] = {};
    float4 rcur[4], rnext[4];

#pragma unroll
    for (int p = 0; p < 4; ++p) {
        int ar = m0 + p * 16 + srow;
        rcur[p] = make_float4(0.f, 0.f, 0.f, 0.f);
        if (ar < M) rcur[p] = *reinterpret_cast<const float4*>(&A[(size_t)ar * 1024 + scol]);
    }
#pragma unroll
    for (int p = 0; p < 4; ++p) {
        ushort4 u;
        u.x = f2bf(rcur[p].x); u.y = f2bf(rcur[p].y); u.z = f2bf(rcur[p].z); u.w = f2bf(rcur[p].w);
        *reinterpret_cast<ushort4*>(&As2[0][p * 16 + srow][scol]) = u;
    }
#pragma unroll
    for (int p = 0; p < 4; ++p) {
        int ar = m0 + p * 16 + srow;
        rcur[p] = make_float4(0.f, 0.f, 0.f, 0.f);
        if (ar < M) rcur[p] = *reinterpret_cast<const float4*>(&A[(size_t)ar * 1024 + 64 + scol]);
    }
    __syncthreads();

    for (int c = 0; c < 16; ++c) {
        const int buf = c & 1;
        if (c < 14) {
            const int k0 = (c + 2) * 64;
#pragma unroll
            for (int p = 0; p < 4; ++p) {
                int ar = m0 + p * 16 + srow;
                rnext[p] = make_float4(0.f, 0.f, 0.f, 0.f);
                if (ar < M) rnext[p] = *reinterpret_cast<const float4*>(&A[(size_t)ar * 1024 + k0 + scol]);
            }
        }
#pragma unroll
        for (int t = 0; t < 2; ++t) {
            const int ks = c * 2 + t;
            short8 afr[4], bfr[4];
#pragma unroll
            for (int fm = 0; fm < 4; ++fm)
                afr[fm] = *reinterpret_cast<const short8*>(&As2[buf][fm * 16 + l16][t * 32 + g * 8]);
#pragma unroll
            for (int fn = 0; fn < 4; ++fn)
                bfr[fn] = Bv[((ks * 4 + wid) * 4 + fn) * 64 + lane];
#pragma unroll
            for (int fm = 0; fm < 4; ++fm)
#pragma unroll
                for (int fn = 0; fn < 4; ++fn)
                    acc[fm][fn] = __builtin_amdgcn_mfma_f32_16x16x32_bf16(
                        afr[fm], bfr[t == 0 ? fn : fn], acc[fm][fn], 0, 0, 0);
        }
        if (c < 15) {
#pragma unroll
            for (int p = 0; p < 4; ++p) {
                ushort4 u;
                u.x = f2bf(rcur[p].x); u.y = f2bf(rcur[p].y);
                u.z = f2bf(rcur[p].z); u.w = f2bf(rcur[p].w);
                *reinterpret_cast<ushort4*>(&As2[buf ^ 1][p * 16 + srow][scol]) = u;
            }
        }
        __syncthreads();
#pragma unroll
        for (int p = 0; p < 4; ++p) rcur[p] = rnext[p];
    }

#pragma unroll
    for (int fm = 0; fm < 4; ++fm) {
#pragma unroll
        for (int r = 0; r < 4; ++r) {
            int row = m0 + fm * 16 + g * 4 + r;
            if (row < M) {
#pragma unroll
                for (int fn = 0; fn < 4; ++fn)
                    P[(size_t)row * 256 + colbase + fn * 16] = f2bf(acc[fm][fn][r]);
            }
        }
    }
}

// ---------- GAT linear via MFMA: single-wave 64-row tiles, no barriers ----------
// MODE 1: IND=20,KS=1,NF=5, cols 80 = xl(40)|xr(40).  MODE 2: IND=40,KS=2,NF=3, cols 48 = xl2(20)|xr2(20)|pad
template <int IND, int KS, int NF, int MODE>
__global__ __launch_bounds__(64) void gat_lin_mfma(
    const float* __restrict__ X, const unsigned short* __restrict__ Bp,
    const float* __restrict__ bl, const float* __restrict__ br,
    float* __restrict__ xl, float* __restrict__ xr, int M)
{
    constexpr int W = KS * 32;
    constexpr int WP = W + 8;
    __shared__ unsigned short xs[64][WP];
    const int lane = threadIdx.x;
    const int m0 = blockIdx.x * 64;
    const int l16 = lane & 15, g = lane >> 4;
    const short8* Bv = reinterpret_cast<const short8*>(Bp);

    // stage X (fp32, coalesced flat float4) -> LDS bf16
    constexpr int NV = 64 * IND / 4 / 64;
#pragma unroll
    for (int i = 0; i < NV; ++i) {
        int q = i * 64 + lane;
        int f = q * 4;
        int row = f / IND, col = f % IND;
        int ar = m0 + row;
        float4 v = make_float4(0.f, 0.f, 0.f, 0.f);
        if (ar < M) v = *reinterpret_cast<const float4*>(&X[(size_t)ar * IND + col]);
        ushort4 u;
        u.x = f2bf(v.x); u.y = f2bf(v.y); u.z = f2bf(v.z); u.w = f2bf(v.w);
        *reinterpret_cast<ushort4*>(&xs[row][col]) = u;
    }
    // zero K padding (cols IND..W) for own row
    ushort4 zz; zz.x = 0; zz.y = 0; zz.z = 0; zz.w = 0;
#pragma unroll
    for (int c = IND; c < W; c += 4)
        *reinterpret_cast<ushort4*>(&xs[lane][c]) = zz;

    f32x4 acc[4][NF] = {};
#pragma unroll
    for (int t = 0; t < KS; ++t) {
        short8 afr[4], bfr[NF];
#pragma unroll
        for (int fm = 0; fm < 4; ++fm)
            afr[fm] = *reinterpret_cast<const short8*>(&xs[fm * 16 + l16][t * 32 + g * 8]);
#pragma unroll
        for (int fn = 0; fn < NF; ++fn)
            bfr[fn] = Bv[(t * NF + fn) * 64 + lane];
#pragma unroll
        for (int fm = 0; fm < 4; ++fm)
#pragma unroll
            for (int fn = 0; fn < NF; ++fn)
                acc[fm][fn] = __builtin_amdgcn_mfma_f32_16x16x32_bf16(
                    afr[fm], bfr[fn], acc[fm][fn], 0, 0, 0);
    }

#pragma unroll
    for (int fm = 0; fm < 4; ++fm) {
#pragma unroll
        for (int r = 0; r < 4; ++r) {
            int row = m0 + fm * 16 + g * 4 + r;
            if (row < M) {
#pragma unroll
                for (int fn = 0; fn < NF; ++fn) {
                    int col = fn * 16 + l16;
                    float v = acc[fm][fn][r];
                    if (MODE == 1) {
                        if (col < 40) xl[(size_t)row * 40 + col] = v + bl[col];
                        else          xr[(size_t)row * 40 + (col - 40)] = v + br[col - 40];
                    } else {
                        if (col < 20)      xl[(size_t)row * 20 + col] = v + bl[col];
                        else if (col < 40) xr[(size_t)row * 20 + (col - 20)] = v + br[col - 20];
                    }
                }
            }
        }
    }
}

// ---------- MLP head via MFMA (z bf16 + addf direct) ----------
__global__ __launch_bounds__(256) void mlp_mfma(
    const unsigned short* __restrict__ z, const float* __restrict__ addf,
    const unsigned short* __restrict__ Bt1p,
    const float* __restrict__ fc1b, const float* __restrict__ bnfg, const float* __restrict__ bnfb,
    const float* __restrict__ fc2W, const float* __restrict__ fc2b,
    float* __restrict__ out, int M)
{
    __shared__ __align__(16) char smem[64 * 169 * 4];
    unsigned short (*zs)[200] = reinterpret_cast<unsigned short(*)[200]>(smem);
    float (*ts)[169] = reinterpret_cast<float(*)[169]>(smem);
    const int tid = threadIdx.x;
    const int wid = tid >> 6, lane = tid & 63;
    const int m0 = blockIdx.x * 64;
    const int l16 = lane & 15, g = lane >> 4;
    const short8* Bv = reinterpret_cast<const short8*>(Bt1p);

#pragma unroll
    for (int p = 0; p < 13; ++p) {
        int idx = p * 256 + tid;
        if (idx < 3200) {
            int row = idx / 50, c4 = (idx % 50) * 4;
            int ar = m0 + row;
            ushort4 u; u.x = 0; u.y = 0; u.z = 0; u.w = 0;
            if (ar < M) {
                if (c4 < 148) {
                    u = *reinterpret_cast<const ushort4*>(&z[(size_t)ar * 168 + c4]);
                } else if (c4 < 168) {
                    float4 v = *reinterpret_cast<const float4*>(&addf[(size_t)ar * 20 + (c4 - 148)]);
                    u.x = f2bf(v.x); u.y = f2bf(v.y); u.z = f2bf(v.z); u.w = f2bf(v.w);
                }
            }
            *reinterpret_cast<ushort4*>(&zs[row][c4]) = u;
        }
    }
    __syncthreads();

    f32x4 acc[4][4] = {};
    if (wid < 3) {
#pragma unroll
        for (int t = 0; t < 6; ++t) {
            short8 afr[4], bfr[4];
#pragma unroll
            for (int fm = 0; fm < 4; ++fm)
                afr[fm] = *reinterpret_cast<const short8*>(&zs[fm * 16 + l16][t * 32 + g * 8]);
#pragma unroll
            for (int fn = 0; fn < 4; ++fn)
                bfr[fn] = Bv[((t * 3 + wid) * 4 + fn) * 64 + lane];
#pragma unroll
            for (int fm = 0; fm < 4; ++fm)
#pragma unroll
                for (int fn = 0; fn < 4; ++fn)
                    acc[fm][fn] = __builtin_amdgcn_mfma_f32_16x16x32_bf16(
                        afr[fm], bfr[fn], acc[fm][fn], 0, 0, 0);
        }
    }
    __syncthreads();
    if (wid < 3) {
        const int colbase = wid * 64 + l16;
#pragma unroll
        for (int fm = 0; fm < 4; ++fm) {
#pragma unroll
            for (int r = 0; r < 4; ++r) {
                int rr = fm * 16 + g * 4 + r;
#pragma unroll
                for (int fn = 0; fn < 4; ++fn) {
                    int col = colbase + fn * 16;
                    if (col < 168) {
                        float v = acc[fm][fn][r] + fc1b[col];
                        v = v * (bnfg[col] * BN_RSQ) + bnfb[col];
                        ts[rr][col] = fmaxf(v, 0.0f);
                    }
                }
            }
        }
    }
    __syncthreads();
    if (tid < 192) {
        int r = tid & 63, c = tid >> 6;
        float acc2 = fc2b[c];
#pragma unroll 4
        for (int k = 0; k < 168; ++k) acc2 += ts[r][k] * fc2W[k * 3 + c];
        int row = m0 + r;
        if (row < M) out[(size_t)row * 3 + c] = acc2;
    }
}

// ---------- exclusive scans (y-fused for both CSRs) ----------
__global__ void scan1(const int* __restrict__ cnt1, const int* __restrict__ cnt2,
                      int* __restrict__ off1, int* __restrict__ off2,
                      int* __restrict__ bsum1, int* __restrict__ bsum2, int M)
{
    __shared__ int sh[SCAN_B];
    int y = blockIdx.y;
    const int* cnt = y ? cnt2 : cnt1;
    int* excl = y ? off2 : off1;
    int* bsum = y ? bsum2 : bsum1;
    int i = blockIdx.x * SCAN_B + threadIdx.x;
    int v = (i < M) ? cnt[i] + y : 0;
    sh[threadIdx.x] = v;
    __syncthreads();
    for (int o = 1; o < SCAN_B; o <<= 1) {
        int t = (threadIdx.x >= o) ? sh[threadIdx.x - o] : 0;
        __syncthreads();
        sh[threadIdx.x] += t;
        __syncthreads();
    }
    if (i < M) excl[i] = sh[threadIdx.x] - v;
    if (threadIdx.x == SCAN_B - 1) bsum[blockIdx.x] = sh[threadIdx.x];
}

__global__ void scan2(int* __restrict__ bsum1, int* __restrict__ bsum2, int nb)
{
    __shared__ int sh[SCAN_B];
    int* bsum = blockIdx.y ? bsum2 : bsum1;
    int v = ((int)threadIdx.x < nb) ? bsum[threadIdx.x] : 0;
    sh[threadIdx.x] = v;
    __syncthreads();
    for (int o = 1; o < SCAN_B; o <<= 1) {
        int t = (threadIdx.x >= o) ? sh[threadIdx.x - o] : 0;
        __syncthreads();
        sh[threadIdx.x] += t;
        __syncthreads();
    }
    if ((int)threadIdx.x < nb) bsum[threadIdx.x] = sh[threadIdx.x] - v;
}

__global__ void scan3(int* __restrict__ off1, int* __restrict__ off2,
                      const int* __restrict__ bsum1, const int* __restrict__ bsum2,
                      const int* __restrict__ cnt1, const int* __restrict__ cnt2,
                      const float* __restrict__ easum, float* __restrict__ eaext,
                      int E, int M)
{
    int y = blockIdx.y;
    int* off = y ? off2 : off1;
    const int* bsum = y ? bsum2 : bsum1;
    const int* cnt = y ? cnt2 : cnt1;
    int i = blockIdx.x * SCAN_B + threadIdx.x;
    if (i < M) {
        int v = off[i] + bsum[blockIdx.x];
        off[i] = v;
        if (i == M - 1) off[M] = v + cnt[i] + y;   // sentinel
        if (y) eaext[E + i] = easum[i] / fmaxf((float)cnt2[i], 1.0f);
    }
}

// ---------- fused CSR fill ----------
__global__ void fill_both(const int* __restrict__ e1s, const int* __restrict__ e1d,
                          const int* __restrict__ e2d,
                          const int* __restrict__ off1, const int* __restrict__ off2,
                          int* __restrict__ cnt1, int* __restrict__ cnt2,
                          int* __restrict__ srcs1, int* __restrict__ eidx2, int E, int Eext)
{
    int t = blockIdx.x * blockDim.x + threadIdx.x;
    if (t < E) {
        int d = e1d[t];
        int pos = atomicSub(&cnt1[d], 1) - 1;
        srcs1[off1[d] + pos] = e1s[t];
    }
    int t2 = t - E;
    if (t2 >= 0 && t2 < Eext) {
        if (t2 < E) {
            int d = e2d[t2];
            int pos = atomicSub(&cnt2[d], 1) - 1;
            eidx2[off2[d] + pos] = t2;
        } else {
            int nn = t2 - E;
            eidx2[off2[nn + 1] - 1] = t2;   // self-loop takes the last slot
        }
    }
}

// ---------- SAGE gather (bf16 P), fused BN/act epilogue into bf16 z ----------
__global__ void sage_gather(const int* __restrict__ srcs1, const int* __restrict__ off1,
                            const unsigned short* __restrict__ P, const float* __restrict__ bl,
                            const float* __restrict__ bng, const float* __restrict__ bnb,
                            unsigned short* __restrict__ z, int N)
{
    int t = blockIdx.x * blockDim.x + threadIdx.x;
    if (t >= N * 32) return;
    int n = t >> 5, g = t & 31;
    int beg = off1[n], end = off1[n + 1];
    float a0 = 0.f, a1 = 0.f, a2 = 0.f, a3 = 0.f;
    for (int j = beg; j < end; ++j) {
        int s = srcs1[j];
        ushort4 v = *reinterpret_cast<const ushort4*>(&P[(size_t)s * 256 + g * 4]);
        a0 += bf2f(v.x); a1 += bf2f(v.y); a2 += bf2f(v.z); a3 += bf2f(v.w);
    }
    float inv = 1.0f / fmaxf((float)(end - beg), 1.0f);
    ushort4 pr = *reinterpret_cast<const ushort4*>(&P[(size_t)n * 256 + 128 + g * 4]);
    float a4[4] = {a0, a1, a2, a3};
    float p4[4] = {bf2f(pr.x), bf2f(pr.y), bf2f(pr.z), bf2f(pr.w)};
    ushort4 zo;
    unsigned short* zp = reinterpret_cast<unsigned short*>(&zo);
#pragma unroll
    for (int k = 0; k < 4; ++k) {
        int cc = g * 4 + k;
        float x = a4[k] * inv + bl[cc] + p4[k];
        x = x * (bng[cc] * BN_RSQ) + bnb[cc];
        zp[k] = f2bf(lrelu(x, 0.01f));
    }
    *reinterpret_cast<ushort4*>(&z[(size_t)n * 168 + g * 4]) = zo;
}

// ---------- fused GATv2 per (node, head): ONE pass, online softmax ----------
template <int H, int C, int MODE>
__global__ void gat_node(const int* __restrict__ eidx2, const int* __restrict__ off2,
                         const int* __restrict__ e2s, const float* __restrict__ eaext,
                         const float* __restrict__ xl, const float* __restrict__ xr,
                         const float* __restrict__ We, const float* __restrict__ att,
                         const float* __restrict__ b,
                         const float* __restrict__ bng, const float* __restrict__ bnb,
                         void* __restrict__ outv, int E, int N)
{
    int t = blockIdx.x * blockDim.x + threadIdx.x;
    if (t >= N * H) return;
    int n = t / H, h = t % H;

    float xrc[C], atth[C], weh[C];
#pragma unroll
    for (int c = 0; c < C; ++c) {
        xrc[c]  = xr[(size_t)n * (H * C) + h * C + c];
        atth[c] = att[h * C + c];
        weh[c]  = We[h * C + c];
    }

    const int beg = off2[n], end = off2[n + 1];

    float mx = -FLT_MAX, den = 0.0f;
    float accv[C] = {};
    for (int j = beg; j < end; ++j) {
        int e = eidx2[j];
        int s = (e < E) ? e2s[e] : (e - E);
        float ea = eaext[e];
        const float* xls = xl + (size_t)s * (H * C) + h * C;
        float xv[C];
        float lg = 0.0f;
#pragma unroll
        for (int c = 0; c < C; ++c) {
            xv[c] = xls[c];
            float m = xv[c] + xrc[c] + ea * weh[c];
            lg += lrelu(m, 0.2f) * atth[c];
        }
        if (lg > mx) {
            float sc = __expf(mx - lg);
            den *= sc;
#pragma unroll
            for (int c = 0; c < C; ++c) accv[c] *= sc;
            mx = lg;
        }
        float ex = __expf(lg - mx);
        den += ex;
#pragma unroll
        for (int c = 0; c < C; ++c) accv[c] += ex * xv[c];
    }
    float inv = 1.0f / (den + 1e-16f);

#pragma unroll
    for (int c = 0; c < C; ++c) {
        int jch = h * C + c;
        float v = accv[c] * inv + b[jch];
        if (MODE == 1) {
            ((float*)outv)[(size_t)n * (H * C) + jch] = lrelu(v, 0.01f);
        } else {
            v = v * (bng[jch] * BN_RSQ) + bnb[jch];
            ((unsigned short*)outv)[(size_t)n * 168 + 128 + jch] = f2bf(lrelu(v, 0.01f));
        }
    }
}

// ---------- launch ----------
extern "C" void kernel_launch(void* const* d_in, const int* in_sizes, int n_in,
                              void* d_out, int out_size, void* d_ws, size_t ws_size,
                              hipStream_t stream)
{
    const float* features = (const float*)d_in[0];
    const int*   e1       = (const int*)d_in[1];
    const int*   e2       = (const int*)d_in[2];
    const float* ef       = (const float*)d_in[3];
    const float* addf     = (const float*)d_in[4];
    const float* sage_Wl  = (const float*)d_in[5];
    const float* sage_bl  = (const float*)d_in[6];
    const float* sage_Wr  = (const float*)d_in[7];
    const float* g1_Wl = (const float*)d_in[8];
    const float* g1_bl = (const float*)d_in[9];
    const float* g1_Wr = (const float*)d_in[10];
    const float* g1_br = (const float*)d_in[11];
    const float* g1_We = (const float*)d_in[12];
    const float* g1_att = (const float*)d_in[13];
    const float* g1_b = (const float*)d_in[14];
    const float* g2_Wl = (const float*)d_in[15];
    const float* g2_bl = (const float*)d_in[16];
    const float* g2_Wr = (const float*)d_in[17];
    const float* g2_br = (const float*)d_in[18];
    const float* g2_We = (const float*)d_in[19];
    const float* g2_att = (const float*)d_in[20];
    const float* g2_b = (const float*)d_in[21];
    const float* fc1_W = (const float*)d_in[22];
    const float* fc1_b = (const float*)d_in[23];
    const float* fc2_W = (const float*)d_in[24];
    const float* fc2_b = (const float*)d_in[25];
    const float* bnx_g = (const float*)d_in[26];
    const float* bnx_b = (const float*)d_in[27];
    const float* bny_g = (const float*)d_in[28];
    const float* bny_b = (const float*)d_in[29];
    const float* bnf_g = (const float*)d_in[30];
    const float* bnf_b = (const float*)d_in[31];

    const int N = in_sizes[0] / 1024;
    const int E = in_sizes[3];
    const int Eext = E + N;
    const int* e1s = e1, *e1d = e1 + E;
    const int* e2s = e2, *e2d = e2 + E;
    const int nb = (N + SCAN_B - 1) / SCAN_B;

    char* wb = (char*)d_ws;
    size_t off = 0;
    auto takeB = [&](size_t bytes) { char* p = wb + off; off = (off + bytes + 255) & ~(size_t)255; return p; };
    unsigned short* P = (unsigned short*)takeB((size_t)N * 256 * 2);
    unsigned short* z = (unsigned short*)takeB((size_t)N * 168 * 2);
    float* eaext = (float*)takeB((size_t)Eext * 4);
    float* xl1   = (float*)takeB((size_t)N * 40 * 4);
    float* xr1   = (float*)takeB((size_t)N * 40 * 4);
    float* y1    = (float*)takeB((size_t)N * 40 * 4);
    float* xl2   = (float*)takeB((size_t)N * 20 * 4);
    float* xr2   = (float*)takeB((size_t)N * 20 * 4);
    unsigned short* Btp  = (unsigned short*)takeB((size_t)256 * 1024 * 2);
    unsigned short* Bt1p = (unsigned short*)takeB((size_t)36864 * 2);
    unsigned short* Bg1  = (unsigned short*)takeB((size_t)2560 * 2);
    unsigned short* Bg2  = (unsigned short*)takeB((size_t)3072 * 2);
    char* zero_beg = wb + off;
    int* cnt1    = (int*)takeB((size_t)N * 4);
    int* cnt2    = (int*)takeB((size_t)N * 4);
    float* easum = (float*)takeB((size_t)N * 4);
    size_t zero_len = (size_t)((wb + off) - zero_beg);
    int* off1  = (int*)takeB((size_t)(N + 1) * 4);
    int* off2  = (int*)takeB((size_t)(N + 1) * 4);
    int* bsum1 = (int*)takeB(SCAN_B * 4);
    int* bsum2 = (int*)takeB(SCAN_B * 4);
    int* srcs1 = (int*)takeB((size_t)E * 4);
    int* eidx2 = (int*)takeB((size_t)Eext * 4);

    const int B = 256;
    const int n16 = (int)(zero_len / 16);
    zero_ws<<<(n16 + B - 1) / B, B, 0, stream>>>((uint4*)zero_beg, n16);

    const int prep_total = 262144 + 36864 + 2560 + 3072 + E;
    prep_all<<<(prep_total + B - 1) / B, B, 0, stream>>>(
        sage_Wl, sage_Wr, Btp, fc1_W, Bt1p,
        g1_Wl, g1_Wr, Bg1, g2_Wl, g2_Wr, Bg2,
        e1d, e2d, ef, cnt1, cnt2, easum, eaext, E);

    scan1<<<dim3(nb, 2), SCAN_B, 0, stream>>>(cnt1, cnt2, off1, off2, bsum1, bsum2, N);
    scan2<<<dim3(1, 2), SCAN_B, 0, stream>>>(bsum1, bsum2, nb);
    scan3<<<dim3(nb, 2), SCAN_B, 0, stream>>>(off1, off2, bsum1, bsum2, cnt1, cnt2,
                                              easum, eaext, E, N);

    fill_both<<<(E + Eext + B - 1) / B, B, 0, stream>>>(e1s, e1d, e2d, off1, off2,
                                                        cnt1, cnt2, srcs1, eidx2, E, Eext);

    const int mtiles = (N + 63) / 64;
    gemm_sage_mfma<<<mtiles, 256, 0, stream>>>(features, Btp, P, N);
    sage_gather<<<(N * 32 + B - 1) / B, B, 0, stream>>>(srcs1, off1, P, sage_bl, bnx_g, bnx_b, z, N);

    gat_lin_mfma<20, 1, 5, 1><<<mtiles, 64, 0, stream>>>(addf, Bg1, g1_bl, g1_br, xl1, xr1, N);
    gat_node<4, 10, 1><<<(N * 4 + B - 1) / B, B, 0, stream>>>(
        eidx2, off2, e2s, eaext, xl1, xr1, g1_We, g1_att, g1_b,
        nullptr, nullptr, (void*)y1, E, N);

    gat_lin_mfma<40, 2, 3, 2><<<mtiles, 64, 0, stream>>>(y1, Bg2, g2_bl, g2_br, xl2, xr2, N);
    gat_node<4, 5, 2><<<(N * 4 + B - 1) / B, B, 0, stream>>>(
        eidx2, off2, e2s, eaext, xl2, xr2, g2_We, g2_att, g2_b,
        bny_g, bny_b, (void*)z, E, N);

    mlp_mfma<<<mtiles, 256, 0, stream>>>(z, addf, Bt1p, fc1_b, bnf_g, bnf_b, fc2_W, fc2_b,
                                         (float*)d_out, N);
}